// Round 3
// baseline (258.306 us; speedup 1.0000x reference)
//
#include <hip/hip_runtime.h>

#define SEQ 4096
#define DIM 128
#define BQ 64
#define BK 64
#define KSTRIDE 136   // 128 + 8 pad (fp16 elems); 272 B row = 17*16 -> aligned + odd dword factor
#define VSTRIDE 72    // 64 + 8 pad;  144 B row = 9*16
#define PSTRIDE 72
#define NKT (SEQ / BK)

typedef __attribute__((ext_vector_type(8))) _Float16 half8;
typedef __attribute__((ext_vector_type(2))) __fp16   fp16x2;   // native return type of cvt_pkrtz
typedef __attribute__((ext_vector_type(4))) float  float4v;
typedef __attribute__((ext_vector_type(4))) unsigned int uint4v;
typedef __attribute__((ext_vector_type(2))) unsigned int uint2v;

// convert+pack two fp32 -> packed fp16 (round-toward-zero), one v_cvt_pkrtz_f16_f32
static __device__ __forceinline__ unsigned int pkh(float a, float b) {
    fp16x2 h = __builtin_amdgcn_cvt_pkrtz(a, b);
    return __builtin_bit_cast(unsigned int, h);
}

__global__ __launch_bounds__(128, 2)
void attn_fa(const float* __restrict__ Qg, const float* __restrict__ Kg,
             const float* __restrict__ Vg, float* __restrict__ Og) {
    __shared__ short Ks[BK * KSTRIDE];   // K tile, row-major [key][d], fp16
    __shared__ short Vt[DIM * VSTRIDE];  // V tile, transposed [d][key], fp16
    __shared__ short Ps[BQ * PSTRIDE];   // P tile, row-major [q][key], fp16

    const int t    = threadIdx.x;
    const int w    = t >> 6;        // wave 0/1
    const int lane = t & 63;
    const int l15  = lane & 15;
    const int quad = lane >> 4;
    const int q8   = quad * 8;
    const int wq   = w * 32;        // this wave's q-row base (2 m-tiles)

    const int b     = blockIdx.x & 7;        // batch -> XCD-sticky for KV L2 locality
    const int qbase = (blockIdx.x >> 3) * BQ;

    const float qs = 0.08838834764831845f * 1.44269504088896340f; // 1/sqrt(128) * log2(e)

    // ---- Q fragments (pre-scaled), register-resident for the whole kernel ----
    half8 qf[2][4];
    {
        const float* Qb = Qg + ((size_t)b * SEQ + qbase + wq) * DIM;
        #pragma unroll
        for (int m = 0; m < 2; ++m) {
            const float* qrow = Qb + (m * 16 + l15) * DIM;
            #pragma unroll
            for (int k = 0; k < 4; ++k) {
                float4v x0 = *(const float4v*)(qrow + k * 32 + q8);
                float4v x1 = *(const float4v*)(qrow + k * 32 + q8 + 4);
                uint4v u;
                u[0] = pkh(x0[0] * qs, x0[1] * qs);
                u[1] = pkh(x0[2] * qs, x0[3] * qs);
                u[2] = pkh(x1[0] * qs, x1[1] * qs);
                u[3] = pkh(x1[2] * qs, x1[3] * qs);
                qf[m][k] = __builtin_bit_cast(half8, u);
            }
        }
    }

    const float4v zero4 = {0.0f, 0.0f, 0.0f, 0.0f};
    float4v o_acc[2][8];
    float4v l_part[2];
    #pragma unroll
    for (int m = 0; m < 2; ++m) {
        l_part[m] = zero4;
        #pragma unroll
        for (int n = 0; n < 8; ++n) o_acc[m][n] = zero4;
    }

    const float* Kb = Kg + (size_t)b * SEQ * DIM;
    const float* Vb = Vg + (size_t)b * SEQ * DIM;

    for (int kt = 0; kt < NKT; ++kt) {
        const size_t kbase = (size_t)kt * BK;
        __syncthreads();   // all waves done reading previous Ks/Vt

        // ---- stage K tile 64x128 fp32 -> fp16 row-major (coalesced reads) ----
        {
            const float4v* Ksrc = (const float4v*)(Kb + kbase * DIM);
            #pragma unroll
            for (int j = 0; j < 8; ++j) {
                int idx = j * 256 + t * 2;          // float4 index, pairs per thread
                float4v x0 = Ksrc[idx];
                float4v x1 = Ksrc[idx + 1];
                int row = idx >> 5;                 // 32 float4 per row
                int col = (idx & 31) * 4;           // element col
                uint4v u;
                u[0] = pkh(x0[0], x0[1]);
                u[1] = pkh(x0[2], x0[3]);
                u[2] = pkh(x1[0], x1[1]);
                u[3] = pkh(x1[2], x1[3]);
                *(uint4v*)&Ks[row * KSTRIDE + col] = u;   // ds_write_b128
            }
        }
        // ---- stage V tile 64x128 fp32 -> fp16 transposed Vt[d][key] ----
        {
            const float* Vsrc = Vb + kbase * DIM;
            const int key4 = (t & 15) * 4;
            const int d0   = (t >> 4) * 16;
            #pragma unroll
            for (int h = 0; h < 2; ++h) {
                float4v vv[4][2];
                #pragma unroll
                for (int i = 0; i < 4; ++i) {
                    vv[i][0] = *(const float4v*)&Vsrc[(key4 + i) * DIM + d0 + h * 8];
                    vv[i][1] = *(const float4v*)&Vsrc[(key4 + i) * DIM + d0 + h * 8 + 4];
                }
                #pragma unroll
                for (int jj = 0; jj < 2; ++jj) {
                    #pragma unroll
                    for (int e = 0; e < 4; ++e) {
                        int d = d0 + h * 8 + jj * 4 + e;
                        uint2v pk;
                        pk[0] = pkh(vv[0][jj][e], vv[1][jj][e]);
                        pk[1] = pkh(vv[2][jj][e], vv[3][jj][e]);
                        *(uint2v*)&Vt[d * VSTRIDE + key4] = pk;   // ds_write_b64
                    }
                }
            }
        }
        __syncthreads();

        // ---- S = Q K^T : A = Q[m][k] (regs), B = K^T from row-major Ks ----
        float4v s[2][4];
        #pragma unroll
        for (int m = 0; m < 2; ++m)
            #pragma unroll
            for (int nt = 0; nt < 4; ++nt) s[m][nt] = zero4;
        #pragma unroll
        for (int k = 0; k < 4; ++k) {
            #pragma unroll
            for (int nt = 0; nt < 4; ++nt) {
                half8 bk = *(const half8*)&Ks[(nt * 16 + l15) * KSTRIDE + k * 32 + q8];
                s[0][nt] = __builtin_amdgcn_mfma_f32_16x16x32_f16(qf[0][k], bk, s[0][nt], 0, 0, 0);
                s[1][nt] = __builtin_amdgcn_mfma_f32_16x16x32_f16(qf[1][k], bk, s[1][nt], 0, 0, 0);
            }
        }

        // ---- P = exp2(S'), accumulate per-lane partial l, stage P as fp16 ----
        #pragma unroll
        for (int m = 0; m < 2; ++m) {
            const int rowb = wq + m * 16 + quad * 4;
            #pragma unroll
            for (int nt = 0; nt < 4; ++nt) {
                const int colo = nt * 16 + l15;
                #pragma unroll
                for (int r = 0; r < 4; r += 2) {
                    float p0 = __builtin_amdgcn_exp2f(s[m][nt][r]);
                    float p1 = __builtin_amdgcn_exp2f(s[m][nt][r + 1]);
                    l_part[m][r]     += p0;
                    l_part[m][r + 1] += p1;
                    unsigned int u = pkh(p0, p1);
                    Ps[(rowb + r)     * PSTRIDE + colo] = (short)(u & 0xFFFFu);
                    Ps[(rowb + r + 1) * PSTRIDE + colo] = (short)(u >> 16);
                }
            }
        }
        __syncthreads();   // wave-local LDS round-trip insurance

        // ---- O += P V : A = P from Ps, B = V from transposed Vt ----
        #pragma unroll
        for (int k2 = 0; k2 < 2; ++k2) {
            half8 a0 = *(const half8*)&Ps[(wq + l15) * PSTRIDE + k2 * 32 + q8];
            half8 a1 = *(const half8*)&Ps[(wq + 16 + l15) * PSTRIDE + k2 * 32 + q8];
            #pragma unroll
            for (int nt2 = 0; nt2 < 8; ++nt2) {
                half8 bv = *(const half8*)&Vt[(nt2 * 16 + l15) * VSTRIDE + k2 * 32 + q8];
                o_acc[0][nt2] = __builtin_amdgcn_mfma_f32_16x16x32_f16(a0, bv, o_acc[0][nt2], 0, 0, 0);
                o_acc[1][nt2] = __builtin_amdgcn_mfma_f32_16x16x32_f16(a1, bv, o_acc[1][nt2], 0, 0, 0);
            }
        }
    }

    // ---- epilogue: reduce row-sums across the 16 lanes of each quad, normalize, store ----
    #pragma unroll
    for (int m = 0; m < 2; ++m) {
        float4v l = l_part[m];
        #pragma unroll
        for (int off = 1; off <= 8; off <<= 1) {
            l[0] += __shfl_xor(l[0], off);
            l[1] += __shfl_xor(l[1], off);
            l[2] += __shfl_xor(l[2], off);
            l[3] += __shfl_xor(l[3], off);
        }
        float* Ob = Og + ((size_t)b * SEQ + qbase + wq + m * 16 + quad * 4) * DIM;
        #pragma unroll
        for (int r = 0; r < 4; ++r) {
            float inv = 1.0f / l[r];
            #pragma unroll
            for (int nt2 = 0; nt2 < 8; ++nt2) {
                Ob[r * DIM + nt2 * 16 + l15] = o_acc[m][nt2][r] * inv;
            }
        }
    }
}

extern "C" void kernel_launch(void* const* d_in, const int* in_sizes, int n_in,
                              void* d_out, int out_size, void* d_ws, size_t ws_size,
                              hipStream_t stream) {
    const float* Q = (const float*)d_in[0];
    const float* K = (const float*)d_in[1];
    const float* V = (const float*)d_in[2];
    float* O = (float*)d_out;
    attn_fa<<<dim3(8 * (SEQ / BQ)), dim3(128), 0, stream>>>(Q, K, V, O);
}

// Round 4
// 193.232 us; speedup vs baseline: 1.3368x; 1.3368x over previous
//
#include <hip/hip_runtime.h>

#define SEQ 4096
#define DIM 128
#define BQ 64
#define BK 64
#define KSTRIDE 136   // 128+8 fp16 elems; row = 272 B = 17*16 (16B-aligned, odd*4 dwords)
#define VSTRIDE 72    // 64+8;  row = 144 B = 9*16
#define PSTRIDE 72

// workspace layout (bytes)
#define KH_OFF 0ull
#define KH_SZ  (8ull * SEQ * DIM * 2)            // 8.39 MB fp16 K
#define VT_OFF (KH_OFF + KH_SZ)
#define VT_SZ  (8ull * SEQ * DIM * 2)            // 8.39 MB fp16 V transposed [b][d][s]
#define OP_OFF (VT_OFF + VT_SZ)
#define OP_SZ  (2ull * 8 * SEQ * DIM * 4)        // 33.6 MB fp32 partial numerators (2 halves)
#define LP_OFF (OP_OFF + OP_SZ)
#define LP_SZ  (2ull * 8 * SEQ * 4)              // 0.26 MB fp32 partial row-sums
#define WS_NEED (LP_OFF + LP_SZ)

typedef __attribute__((ext_vector_type(8))) _Float16 half8;
typedef __attribute__((ext_vector_type(2))) __fp16   fp16x2;
typedef __attribute__((ext_vector_type(4))) float  float4v;
typedef __attribute__((ext_vector_type(4))) unsigned int uint4v;
typedef __attribute__((ext_vector_type(2))) unsigned int uint2v;

static __device__ __forceinline__ unsigned int pkh(float a, float b) {
    fp16x2 h = __builtin_amdgcn_cvt_pkrtz(a, b);
    return __builtin_bit_cast(unsigned int, h);
}

// ---------------- prepass: K -> fp16, V -> fp16 transposed [b][d][s] ----------------
__global__ __launch_bounds__(256)
void prepass(const float* __restrict__ Kg, const float* __restrict__ Vg,
             short* __restrict__ Kh, short* __restrict__ VtG) {
    __shared__ short Ts[DIM * VSTRIDE];
    const int t  = threadIdx.x;
    const int b  = blockIdx.x & 7;
    const int s0 = (blockIdx.x >> 3) * 64;

    // K tile: 64 rows x 128 fp32 -> fp16, same layout
    {
        const float4v* src = (const float4v*)(Kg + ((size_t)b * SEQ + s0) * DIM);
        uint4v* dst = (uint4v*)(Kh + ((size_t)b * SEQ + s0) * DIM);
        #pragma unroll
        for (int j = 0; j < 4; ++j) {
            int idx = j * 256 + t;              // 1024 x 16B chunks
            float4v x0 = src[idx * 2];
            float4v x1 = src[idx * 2 + 1];
            uint4v u;
            u[0] = pkh(x0[0], x0[1]); u[1] = pkh(x0[2], x0[3]);
            u[2] = pkh(x1[0], x1[1]); u[3] = pkh(x1[2], x1[3]);
            dst[idx] = u;
        }
    }
    // V tile: 64 s x 128 d -> LDS transposed fp16
    {
        const float4v* src = (const float4v*)(Vg + ((size_t)b * SEQ + s0) * DIM);
        #pragma unroll
        for (int j = 0; j < 8; ++j) {
            int f4 = j * 256 + t;               // 2048 float4 = 64 rows x 32
            int sl = f4 >> 5;
            int dc = (f4 & 31) * 4;
            float4v x = src[f4];
            unsigned int u01 = pkh(x[0], x[1]);
            unsigned int u23 = pkh(x[2], x[3]);
            Ts[(dc + 0) * VSTRIDE + sl] = (short)(u01 & 0xFFFFu);
            Ts[(dc + 1) * VSTRIDE + sl] = (short)(u01 >> 16);
            Ts[(dc + 2) * VSTRIDE + sl] = (short)(u23 & 0xFFFFu);
            Ts[(dc + 3) * VSTRIDE + sl] = (short)(u23 >> 16);
        }
    }
    __syncthreads();
    // write transposed tile: VtG[b][d][s0:s0+64]
    #pragma unroll
    for (int j = 0; j < 4; ++j) {
        int idx = j * 256 + t;                  // 1024 x 16B chunks (128 d x 4)
        int d = idx >> 3;
        int c = idx & 7;
        uint4v val = *(const uint4v*)&Ts[d * VSTRIDE + c * 8];
        *(uint4v*)(VtG + ((size_t)b * DIM + d) * SEQ + s0 + c * 8) = val;
    }
}

// ---------------- main flash kernel, split-K x2, Ps aliased into Ks ----------------
__global__ __launch_bounds__(128, 2)
void attn_fa2(const float* __restrict__ Qg, const short* __restrict__ Kh,
              const short* __restrict__ VtG, float* __restrict__ Op,
              float* __restrict__ lp) {
    __shared__ short Ks[BK * KSTRIDE];   // 17.4 KB; Ps[64][72] aliased at base
    __shared__ short Vt[DIM * VSTRIDE];  // 18.4 KB
    short* Ps = Ks;

    const int t    = threadIdx.x;
    const int w    = t >> 6;
    const int lane = t & 63;
    const int l15  = lane & 15;
    const int quad = lane >> 4;
    const int q8   = quad * 8;
    const int wq   = w * 32;

    const int b     = blockIdx.x & 7;
    const int half  = (blockIdx.x >> 3) & 1;
    const int qbase = (blockIdx.x >> 4) * BQ;
    const int kb0   = half * (SEQ / 2);

    const float qs = 0.08838834764831845f * 1.44269504088896340f;

    // Q fragments (pre-scaled fp16), register-resident
    half8 qf[2][4];
    {
        const float* Qb = Qg + ((size_t)b * SEQ + qbase + wq) * DIM;
        #pragma unroll
        for (int m = 0; m < 2; ++m) {
            const float* qrow = Qb + (m * 16 + l15) * DIM;
            #pragma unroll
            for (int k = 0; k < 4; ++k) {
                float4v x0 = *(const float4v*)(qrow + k * 32 + q8);
                float4v x1 = *(const float4v*)(qrow + k * 32 + q8 + 4);
                uint4v u;
                u[0] = pkh(x0[0] * qs, x0[1] * qs);
                u[1] = pkh(x0[2] * qs, x0[3] * qs);
                u[2] = pkh(x1[0] * qs, x1[1] * qs);
                u[3] = pkh(x1[2] * qs, x1[3] * qs);
                qf[m][k] = __builtin_bit_cast(half8, u);
            }
        }
    }

    const float4v zero4 = {0.0f, 0.0f, 0.0f, 0.0f};
    float4v o_acc[2][8];
    float4v l_part[2];
    #pragma unroll
    for (int m = 0; m < 2; ++m) {
        l_part[m] = zero4;
        #pragma unroll
        for (int n = 0; n < 8; ++n) o_acc[m][n] = zero4;
    }

    const short* Khb = Kh + (size_t)b * SEQ * DIM;
    const short* Vtb = VtG + (size_t)b * DIM * SEQ;

    for (int kt = 0; kt < (SEQ / 2) / BK; ++kt) {
        const int kbase = kb0 + kt * BK;
        __syncthreads();   // prior PV reads of Ps/Vt done before restage

        // stage K tile (fp16, straight copy): 1024 x 16B chunks
        {
            const short* src = Khb + (size_t)kbase * DIM;
            #pragma unroll
            for (int j = 0; j < 8; ++j) {
                int idx = j * 128 + t;
                int row = idx >> 4;
                int c   = idx & 15;
                uint4v v = *(const uint4v*)(src + row * DIM + c * 8);
                *(uint4v*)&Ks[row * KSTRIDE + c * 8] = v;
            }
        }
        // stage V tile from transposed global: 1024 x 16B chunks
        {
            #pragma unroll
            for (int j = 0; j < 8; ++j) {
                int idx = j * 128 + t;
                int d = idx >> 3;
                int c = idx & 7;
                uint4v v = *(const uint4v*)(Vtb + (size_t)d * SEQ + kbase + c * 8);
                *(uint4v*)&Vt[d * VSTRIDE + c * 8] = v;
            }
        }
        __syncthreads();

        // S = Q K^T
        float4v s[2][4];
        #pragma unroll
        for (int m = 0; m < 2; ++m)
            #pragma unroll
            for (int nt = 0; nt < 4; ++nt) s[m][nt] = zero4;
        #pragma unroll
        for (int k = 0; k < 4; ++k) {
            #pragma unroll
            for (int nt = 0; nt < 4; ++nt) {
                half8 bk = *(const half8*)&Ks[(nt * 16 + l15) * KSTRIDE + k * 32 + q8];
                s[0][nt] = __builtin_amdgcn_mfma_f32_16x16x32_f16(qf[0][k], bk, s[0][nt], 0, 0, 0);
                s[1][nt] = __builtin_amdgcn_mfma_f32_16x16x32_f16(qf[1][k], bk, s[1][nt], 0, 0, 0);
            }
        }
        __syncthreads();   // all waves done reading Ks before Ps overwrites it

        // P = exp2(S), partial l, stage P (fp16) into Ps (aliased)
        #pragma unroll
        for (int m = 0; m < 2; ++m) {
            const int rowb = wq + m * 16 + quad * 4;
            #pragma unroll
            for (int nt = 0; nt < 4; ++nt) {
                const int colo = nt * 16 + l15;
                #pragma unroll
                for (int r = 0; r < 4; r += 2) {
                    float p0 = __builtin_amdgcn_exp2f(s[m][nt][r]);
                    float p1 = __builtin_amdgcn_exp2f(s[m][nt][r + 1]);
                    l_part[m][r]     += p0;
                    l_part[m][r + 1] += p1;
                    unsigned int u = pkh(p0, p1);
                    Ps[(rowb + r)     * PSTRIDE + colo] = (short)(u & 0xFFFFu);
                    Ps[(rowb + r + 1) * PSTRIDE + colo] = (short)(u >> 16);
                }
            }
        }
        // wave-local Ps round-trip: each wave reads only rows it wrote; lgkmcnt ordering suffices

        // O += P V
        #pragma unroll
        for (int k2 = 0; k2 < 2; ++k2) {
            half8 a0 = *(const half8*)&Ps[(wq + l15) * PSTRIDE + k2 * 32 + q8];
            half8 a1 = *(const half8*)&Ps[(wq + 16 + l15) * PSTRIDE + k2 * 32 + q8];
            #pragma unroll
            for (int nt2 = 0; nt2 < 8; ++nt2) {
                half8 bv = *(const half8*)&Vt[(nt2 * 16 + l15) * VSTRIDE + k2 * 32 + q8];
                o_acc[0][nt2] = __builtin_amdgcn_mfma_f32_16x16x32_f16(a0, bv, o_acc[0][nt2], 0, 0, 0);
                o_acc[1][nt2] = __builtin_amdgcn_mfma_f32_16x16x32_f16(a1, bv, o_acc[1][nt2], 0, 0, 0);
            }
        }
    }

    // epilogue: reduce l over 16 lanes, store UNNORMALIZED partials + l
    #pragma unroll
    for (int m = 0; m < 2; ++m) {
        float4v l = l_part[m];
        #pragma unroll
        for (int off = 1; off <= 8; off <<= 1) {
            l[0] += __shfl_xor(l[0], off);
            l[1] += __shfl_xor(l[1], off);
            l[2] += __shfl_xor(l[2], off);
            l[3] += __shfl_xor(l[3], off);
        }
        const int row0 = qbase + wq + m * 16 + quad * 4;
        float* Ob = Op + (((size_t)half * 8 + b) * SEQ + row0) * DIM;
        #pragma unroll
        for (int r = 0; r < 4; ++r) {
            #pragma unroll
            for (int nt2 = 0; nt2 < 8; ++nt2) {
                Ob[r * DIM + nt2 * 16 + l15] = o_acc[m][nt2][r];
            }
        }
        if (l15 == 0) {
            #pragma unroll
            for (int r = 0; r < 4; ++r)
                lp[((size_t)half * 8 + b) * SEQ + row0 + r] = l[r];
        }
    }
}

// ---------------- combine: O = (n0+n1)/(l0+l1) ----------------
__global__ __launch_bounds__(256)
void combine(const float4v* __restrict__ Op, const float* __restrict__ lp,
             float4v* __restrict__ Out) {
    const size_t idx = (size_t)blockIdx.x * 256 + threadIdx.x;   // float4 units
    const size_t srow = idx >> 5;                                // (b*SEQ + q)
    float l = lp[srow] + lp[srow + 8 * SEQ];
    float inv = 1.0f / l;
    float4v n0 = Op[idx];
    float4v n1 = Op[idx + 8ull * SEQ * DIM / 4];
    float4v o;
    o[0] = (n0[0] + n1[0]) * inv;
    o[1] = (n0[1] + n1[1]) * inv;
    o[2] = (n0[2] + n1[2]) * inv;
    o[3] = (n0[3] + n1[3]) * inv;
    Out[idx] = o;
}

// ---------------- fallback (round-3 kernel) if workspace too small ----------------
__global__ __launch_bounds__(128, 2)
void attn_fa_v1(const float* __restrict__ Qg, const float* __restrict__ Kg,
                const float* __restrict__ Vg, float* __restrict__ Og) {
    __shared__ short Ks[BK * KSTRIDE];
    __shared__ short Vt[DIM * VSTRIDE];
    __shared__ short Ps2[BQ * PSTRIDE];

    const int t    = threadIdx.x;
    const int w    = t >> 6;
    const int lane = t & 63;
    const int l15  = lane & 15;
    const int quad = lane >> 4;
    const int q8   = quad * 8;
    const int wq   = w * 32;
    const int b     = blockIdx.x & 7;
    const int qbase = (blockIdx.x >> 3) * BQ;
    const float qs = 0.08838834764831845f * 1.44269504088896340f;

    half8 qf[2][4];
    {
        const float* Qb = Qg + ((size_t)b * SEQ + qbase + wq) * DIM;
        #pragma unroll
        for (int m = 0; m < 2; ++m) {
            const float* qrow = Qb + (m * 16 + l15) * DIM;
            #pragma unroll
            for (int k = 0; k < 4; ++k) {
                float4v x0 = *(const float4v*)(qrow + k * 32 + q8);
                float4v x1 = *(const float4v*)(qrow + k * 32 + q8 + 4);
                uint4v u;
                u[0] = pkh(x0[0] * qs, x0[1] * qs);
                u[1] = pkh(x0[2] * qs, x0[3] * qs);
                u[2] = pkh(x1[0] * qs, x1[1] * qs);
                u[3] = pkh(x1[2] * qs, x1[3] * qs);
                qf[m][k] = __builtin_bit_cast(half8, u);
            }
        }
    }
    const float4v zero4 = {0.0f, 0.0f, 0.0f, 0.0f};
    float4v o_acc[2][8];
    float4v l_part[2];
    #pragma unroll
    for (int m = 0; m < 2; ++m) {
        l_part[m] = zero4;
        #pragma unroll
        for (int n = 0; n < 8; ++n) o_acc[m][n] = zero4;
    }
    const float* Kb = Kg + (size_t)b * SEQ * DIM;
    const float* Vb = Vg + (size_t)b * SEQ * DIM;

    for (int kt = 0; kt < SEQ / BK; ++kt) {
        const size_t kbase = (size_t)kt * BK;
        __syncthreads();
        {
            const float4v* Ksrc = (const float4v*)(Kb + kbase * DIM);
            #pragma unroll
            for (int j = 0; j < 8; ++j) {
                int idx = j * 256 + t * 2;
                float4v x0 = Ksrc[idx];
                float4v x1 = Ksrc[idx + 1];
                int row = idx >> 5;
                int col = (idx & 31) * 4;
                uint4v u;
                u[0] = pkh(x0[0], x0[1]); u[1] = pkh(x0[2], x0[3]);
                u[2] = pkh(x1[0], x1[1]); u[3] = pkh(x1[2], x1[3]);
                *(uint4v*)&Ks[row * KSTRIDE + col] = u;
            }
        }
        {
            const float* Vsrc = Vb + kbase * DIM;
            const int key4 = (t & 15) * 4;
            const int d0   = (t >> 4) * 16;
            #pragma unroll
            for (int h = 0; h < 2; ++h) {
                float4v vv[4][2];
                #pragma unroll
                for (int i = 0; i < 4; ++i) {
                    vv[i][0] = *(const float4v*)&Vsrc[(key4 + i) * DIM + d0 + h * 8];
                    vv[i][1] = *(const float4v*)&Vsrc[(key4 + i) * DIM + d0 + h * 8 + 4];
                }
                #pragma unroll
                for (int jj = 0; jj < 2; ++jj) {
                    #pragma unroll
                    for (int e = 0; e < 4; ++e) {
                        int d = d0 + h * 8 + jj * 4 + e;
                        uint2v pk;
                        pk[0] = pkh(vv[0][jj][e], vv[1][jj][e]);
                        pk[1] = pkh(vv[2][jj][e], vv[3][jj][e]);
                        *(uint2v*)&Vt[d * VSTRIDE + key4] = pk;
                    }
                }
            }
        }
        __syncthreads();
        float4v s[2][4];
        #pragma unroll
        for (int m = 0; m < 2; ++m)
            #pragma unroll
            for (int nt = 0; nt < 4; ++nt) s[m][nt] = zero4;
        #pragma unroll
        for (int k = 0; k < 4; ++k) {
            #pragma unroll
            for (int nt = 0; nt < 4; ++nt) {
                half8 bk = *(const half8*)&Ks[(nt * 16 + l15) * KSTRIDE + k * 32 + q8];
                s[0][nt] = __builtin_amdgcn_mfma_f32_16x16x32_f16(qf[0][k], bk, s[0][nt], 0, 0, 0);
                s[1][nt] = __builtin_amdgcn_mfma_f32_16x16x32_f16(qf[1][k], bk, s[1][nt], 0, 0, 0);
            }
        }
        #pragma unroll
        for (int m = 0; m < 2; ++m) {
            const int rowb = wq + m * 16 + quad * 4;
            #pragma unroll
            for (int nt = 0; nt < 4; ++nt) {
                const int colo = nt * 16 + l15;
                #pragma unroll
                for (int r = 0; r < 4; r += 2) {
                    float p0 = __builtin_amdgcn_exp2f(s[m][nt][r]);
                    float p1 = __builtin_amdgcn_exp2f(s[m][nt][r + 1]);
                    l_part[m][r]     += p0;
                    l_part[m][r + 1] += p1;
                    unsigned int u = pkh(p0, p1);
                    Ps2[(rowb + r)     * PSTRIDE + colo] = (short)(u & 0xFFFFu);
                    Ps2[(rowb + r + 1) * PSTRIDE + colo] = (short)(u >> 16);
                }
            }
        }
        __syncthreads();
        #pragma unroll
        for (int k2 = 0; k2 < 2; ++k2) {
            half8 a0 = *(const half8*)&Ps2[(wq + l15) * PSTRIDE + k2 * 32 + q8];
            half8 a1 = *(const half8*)&Ps2[(wq + 16 + l15) * PSTRIDE + k2 * 32 + q8];
            #pragma unroll
            for (int nt2 = 0; nt2 < 8; ++nt2) {
                half8 bv = *(const half8*)&Vt[(nt2 * 16 + l15) * VSTRIDE + k2 * 32 + q8];
                o_acc[0][nt2] = __builtin_amdgcn_mfma_f32_16x16x32_f16(a0, bv, o_acc[0][nt2], 0, 0, 0);
                o_acc[1][nt2] = __builtin_amdgcn_mfma_f32_16x16x32_f16(a1, bv, o_acc[1][nt2], 0, 0, 0);
            }
        }
    }
    #pragma unroll
    for (int m = 0; m < 2; ++m) {
        float4v l = l_part[m];
        #pragma unroll
        for (int off = 1; off <= 8; off <<= 1) {
            l[0] += __shfl_xor(l[0], off);
            l[1] += __shfl_xor(l[1], off);
            l[2] += __shfl_xor(l[2], off);
            l[3] += __shfl_xor(l[3], off);
        }
        float* Ob = Og + ((size_t)b * SEQ + qbase + wq + m * 16 + quad * 4) * DIM;
        #pragma unroll
        for (int r = 0; r < 4; ++r) {
            float inv = 1.0f / l[r];
            #pragma unroll
            for (int nt2 = 0; nt2 < 8; ++nt2)
                Ob[r * DIM + nt2 * 16 + l15] = o_acc[m][nt2][r] * inv;
        }
    }
}

extern "C" void kernel_launch(void* const* d_in, const int* in_sizes, int n_in,
                              void* d_out, int out_size, void* d_ws, size_t ws_size,
                              hipStream_t stream) {
    const float* Q = (const float*)d_in[0];
    const float* K = (const float*)d_in[1];
    const float* V = (const float*)d_in[2];
    float* O = (float*)d_out;

    if (ws_size >= WS_NEED) {
        char* ws = (char*)d_ws;
        short* Kh  = (short*)(ws + KH_OFF);
        short* VtG = (short*)(ws + VT_OFF);
        float* Op  = (float*)(ws + OP_OFF);
        float* lp  = (float*)(ws + LP_OFF);
        prepass<<<dim3(8 * (SEQ / 64)), dim3(256), 0, stream>>>(K, V, Kh, VtG);
        attn_fa2<<<dim3(8 * 2 * (SEQ / BQ)), dim3(128), 0, stream>>>(Q, Kh, VtG, Op, lp);
        combine<<<dim3((8 * SEQ * DIM / 4) / 256), dim3(256), 0, stream>>>(
            (const float4v*)Op, lp, (float4v*)O);
    } else {
        attn_fa_v1<<<dim3(8 * (SEQ / BQ)), dim3(128), 0, stream>>>(Q, K, V, O);
    }
}